// Round 5
// baseline (134.395 us; speedup 1.0000x reference)
//
#include <hip/hip_runtime.h>
#include <hip/hip_bf16.h>
#include <math.h>

#define T_    100
#define D_    50
#define H_    30
#define HALF  5120
#define EMB_  20
#define NEMB_ 10
#define OUT_  10

typedef _Float16 h2    __attribute__((ext_vector_type(2)));
typedef _Float16 f16x8 __attribute__((ext_vector_type(8)));
typedef float    f32x4 __attribute__((ext_vector_type(4)));

union FR  { f16x8 v; h2 p[4]; float4 f4; };
union W64 { h2 hh[2]; float2 f2; };

__device__ __forceinline__ h2 pk(float a, float b) {
    return __builtin_bit_cast(h2, __builtin_amdgcn_cvt_pkrtz(a, b));
}

// named-member x-load buffer (rule: no runtime-indexed arrays -> registers)
struct XR { float2 a0, a1, a2, a3, b0, b1, b2, b3; };

// ---------------------------------------------------------------------------
// GRU: 1 wave per block, 16 sequences per wave. 640 blocks.
// Swapped MFMA: C[g][s] = Wext[g][k] * Bext[s][k]; gate rows padded to
// g = gate*32 + j so lane (s = l&15, q = l>>4) holds the complete (r,z,n)
// triple for j in {16u + 4q + r}. No cross-lane ops, no barriers in the loop.
// Biases fold into MFMA: Hext[s][30] = 1.0 -> b_hh; x col 50 = 1.0 -> b_ih.
// ---------------------------------------------------------------------------
__global__ __launch_bounds__(64) void gru_kernel(
    const float* __restrict__ input1, const float* __restrict__ input2,
    const float* __restrict__ W_ih,  const float* __restrict__ W_hh,
    const float* __restrict__ b_ih,  const float* __restrict__ b_hh,
    float* __restrict__ emb1_out,    // [5120][30]
    float* __restrict__ h2_out)      // [5120][30]
{
    const int lane = threadIdx.x & 63;
    const int s    = lane & 15;          // seq within wave (and frag row m/n)
    const int q    = lane >> 4;          // k-slice / C row-quad
    const int n    = blockIdx.x * 16 + s;

    __shared__ __align__(16) _Float16 Wst [96 * 64];  // W_ih ext (12 KB)
    __shared__ __align__(16) _Float16 Whst[96 * 32];  // W_hh ext (6 KB)
    __shared__ __align__(16) _Float16 Hl  [16 * 40];  // h rows, stride 40

    // ---- zero W staging (pad rows j=30,31 of each gate block stay 0) ----
    for (int i = lane; i < 1536; i += 64) ((unsigned long long*)Wst)[i]  = 0ull;
    for (int i = lane; i < 768;  i += 64) ((unsigned long long*)Whst)[i] = 0ull;

    // ---- stage W_ih: ext row ge = gate*32 + j, col 50 = b_ih ----
    for (int i = 0; i < 71; ++i) {
        int idx = lane + i * 64;
        if (idx < 4500) {
            int rw = idx / 50, k = idx - rw * 50;
            int ge = rw + 2 * (rw / 30);
            Wst[ge * 64 + k] = (_Float16)W_ih[idx];
        }
    }
    for (int i = 0; i < 2; ++i) {
        int idx = lane + i * 64;
        if (idx < 90) { int ge = idx + 2 * (idx / 30); Wst[ge * 64 + 50] = (_Float16)b_ih[idx]; }
    }
    // ---- stage W_hh: col 30 = b_hh, col 31 = 0 ----
    for (int i = 0; i < 43; ++i) {
        int idx = lane + i * 64;
        if (idx < 2700) {
            int rw = idx / 30, k = idx - rw * 30;
            int ge = rw + 2 * (rw / 30);
            Whst[ge * 32 + k] = (_Float16)W_hh[idx];
        }
    }
    for (int i = 0; i < 2; ++i) {
        int idx = lane + i * 64;
        if (idx < 90) { int ge = idx + 2 * (idx / 30); Whst[ge * 32 + 30] = (_Float16)b_hh[idx]; }
    }
    // ---- h0 = 0; Hl[s][30] = 1.0 (bias one), [31] = 0 ----
    if (lane < 16) {
        for (int j = 0; j < 15; ++j) *(h2*)&Hl[lane * 40 + 2 * j] = pk(0.f, 0.f);
        *(h2*)&Hl[lane * 40 + 30] = pk(1.f, 0.f);
    }
    __syncthreads();

    // ---- A-fragments (weights) into registers ----
    FR wih[6][2], whh[6];
    #pragma unroll
    for (int nt = 0; nt < 6; ++nt) {
        wih[nt][0].f4 = *(const float4*)&Wst [(nt * 16 + s) * 64 + q * 8];
        wih[nt][1].f4 = *(const float4*)&Wst [(nt * 16 + s) * 64 + 32 + q * 8];
        whh[nt].f4    = *(const float4*)&Whst[(nt * 16 + s) * 32 + q * 8];
    }

    // ---- per-lane sequence pointer ----
    const float* xp = (n < HALF) ? input1 + (size_t)n * (T_ * D_)
                                 : input2 + (size_t)(n - HALF) * (T_ * D_);

    auto load_x = [&](int t, XR& X) {
        const float* r = xp + t * D_;
        X.a0 = *(const float2*)(r + q * 8 + 0);
        X.a1 = *(const float2*)(r + q * 8 + 2);
        X.a2 = *(const float2*)(r + q * 8 + 4);
        X.a3 = *(const float2*)(r + q * 8 + 6);
        if (q < 2) {
            X.b0 = *(const float2*)(r + 32 + q * 8 + 0);
            X.b1 = *(const float2*)(r + 32 + q * 8 + 2);
            X.b2 = *(const float2*)(r + 32 + q * 8 + 4);
            X.b3 = *(const float2*)(r + 32 + q * 8 + 6);
        } else if (q == 2) {
            X.b0 = *(const float2*)(r + 48);          // d 48,49
        }
    };
    auto build = [&](const XR& X, FR& x0, FR& x1) {
        x0.p[0] = pk(X.a0.x, X.a0.y); x0.p[1] = pk(X.a1.x, X.a1.y);
        x0.p[2] = pk(X.a2.x, X.a2.y); x0.p[3] = pk(X.a3.x, X.a3.y);
        if (q < 2) {
            x1.p[0] = pk(X.b0.x, X.b0.y); x1.p[1] = pk(X.b1.x, X.b1.y);
            x1.p[2] = pk(X.b2.x, X.b2.y); x1.p[3] = pk(X.b3.x, X.b3.y);
        } else if (q == 2) {
            x1.p[0] = pk(X.b0.x, X.b0.y); x1.p[1] = pk(1.f, 0.f);   // d50 = bias
            x1.p[2] = pk(0.f, 0.f);       x1.p[3] = pk(0.f, 0.f);
        } else {
            x1.p[0] = pk(0.f, 0.f); x1.p[1] = pk(0.f, 0.f);
            x1.p[2] = pk(0.f, 0.f); x1.p[3] = pk(0.f, 0.f);
        }
    };

    float hold[8] = {0.f, 0.f, 0.f, 0.f, 0.f, 0.f, 0.f, 0.f};

    auto step = [&](const FR& x0, const FR& x1) {
        FR bh;
        bh.f4 = *(const float4*)&Hl[s * 40 + q * 8];
        f32x4 arz[4], anh[2], anx[2];
        #pragma unroll
        for (int nt = 0; nt < 4; ++nt) {                 // r,z gates: K = h + x
            f32x4 acc = {0.f, 0.f, 0.f, 0.f};
            acc = __builtin_amdgcn_mfma_f32_16x16x32_f16(whh[nt].v,    bh.v, acc, 0, 0, 0);
            acc = __builtin_amdgcn_mfma_f32_16x16x32_f16(wih[nt][0].v, x0.v, acc, 0, 0, 0);
            acc = __builtin_amdgcn_mfma_f32_16x16x32_f16(wih[nt][1].v, x1.v, acc, 0, 0, 0);
            arz[nt] = acc;
        }
        #pragma unroll
        for (int u = 0; u < 2; ++u) {                    // n gate: h and x SEPARATE
            f32x4 ah = {0.f, 0.f, 0.f, 0.f}, ax = {0.f, 0.f, 0.f, 0.f};
            ah = __builtin_amdgcn_mfma_f32_16x16x32_f16(whh[4 + u].v,    bh.v, ah, 0, 0, 0);
            ax = __builtin_amdgcn_mfma_f32_16x16x32_f16(wih[4 + u][0].v, x0.v, ax, 0, 0, 0);
            ax = __builtin_amdgcn_mfma_f32_16x16x32_f16(wih[4 + u][1].v, x1.v, ax, 0, 0, 0);
            anh[u] = ah; anx[u] = ax;
        }
        #pragma unroll
        for (int u = 0; u < 2; ++u) {
            #pragma unroll
            for (int r = 0; r < 4; ++r) {                // j = 16u + 4q + r
                const float rg = __builtin_amdgcn_rcpf(1.f + __expf(-arz[u][r]));
                const float zg = __builtin_amdgcn_rcpf(1.f + __expf(-arz[2 + u][r]));
                const float aa = fmaf(rg, anh[u][r], anx[u][r]);
                const float th = fmaf(-2.f, __builtin_amdgcn_rcpf(1.f + __expf(2.f * aa)), 1.f);
                hold[u * 4 + r] = fmaf(zg, hold[u * 4 + r] - th, th);
            }
        }
        W64 w0, w1;
        w0.hh[0] = pk(hold[0], hold[1]); w0.hh[1] = pk(hold[2], hold[3]);
        *(float2*)&Hl[s * 40 + 4 * q] = w0.f2;           // j = 4q..4q+3
        if (q < 3) {
            w1.hh[0] = pk(hold[4], hold[5]); w1.hh[1] = pk(hold[6], hold[7]);
            *(float2*)&Hl[s * 40 + 16 + 4 * q] = w1.f2;  // j = 16+4q..+3
        } else {
            *(h2*)&Hl[s * 40 + 28] = pk(hold[4], hold[5]); // j = 28,29 only
        }
    };

    // ---- 100 steps, 2-step software pipeline on x loads ----
    XR X0, X1;
    load_x(0, X0);
    load_x(1, X1);
    #pragma unroll 1
    for (int k2 = 0; k2 < 50; ++k2) {
        FR x0, x1;
        build(X0, x0, x1);
        if (k2 < 49) load_x(2 * k2 + 2, X0);
        step(x0, x1);
        build(X1, x0, x1);
        if (k2 < 49) load_x(2 * k2 + 3, X1);
        step(x0, x1);
    }

    // ---- final hidden out (f32 from registers) ----
    float* outp = (n < HALF) ? emb1_out + (size_t)n * H_
                             : h2_out + (size_t)(n - HALF) * H_;
    #pragma unroll
    for (int u = 0; u < 2; ++u)
        #pragma unroll
        for (int r = 0; r < 4; ++r) {
            const int j = 16 * u + 4 * q + r;
            if (j < H_) outp[j] = hold[u * 4 + r];
        }
}

// ---------------------------------------------------------------------------
// MLP head (unchanged): one row per block.
// ---------------------------------------------------------------------------
__global__ __launch_bounds__(64) void mlp_kernel(
    const float* __restrict__ h2i,  // [512][300]
    const float* __restrict__ W1, const float* __restrict__ b1,
    const float* __restrict__ W2, const float* __restrict__ b2,
    const float* __restrict__ W3, const float* __restrict__ b3,
    float* __restrict__ logit)      // [512][10]
{
    const int b    = blockIdx.x;
    const int lane = threadIdx.x;
    __shared__ float e2[300];
    const float* row = h2i + (size_t)b * 300;
    #pragma unroll
    for (int i = lane; i < 75; i += 64)
        *(float4*)&e2[i * 4] = *(const float4*)(row + i * 4);
    __syncthreads();

    const float kInvSqrt2 = 0.70710678118654752f;
    float y1 = 0.f;
    if (lane < EMB_) {
        float acc = b1[lane];
        const float* wp = W1 + lane * 300;
        #pragma unroll
        for (int qq = 0; qq < 75; ++qq) {
            float4 wv = *(const float4*)(wp + qq * 4);
            acc += wv.x * e2[qq*4 + 0] + wv.y * e2[qq*4 + 1]
                 + wv.z * e2[qq*4 + 2] + wv.w * e2[qq*4 + 3];
        }
        y1 = 0.5f * acc * (1.f + erff(acc * kInvSqrt2));
    }
    float acc2 = (lane < NEMB_) ? b2[lane] : 0.f;
    #pragma unroll
    for (int e = 0; e < EMB_; ++e) {
        const float v = __shfl(y1, e);
        if (lane < NEMB_) acc2 += v * W2[lane * EMB_ + e];
    }
    const float y2 = 0.5f * acc2 * (1.f + erff(acc2 * kInvSqrt2));
    float acc3 = (lane < OUT_) ? b3[lane] : 0.f;
    #pragma unroll
    for (int e = 0; e < NEMB_; ++e) {
        const float v = __shfl(y2, e);
        if (lane < OUT_) acc3 += v * W3[lane * NEMB_ + e];
    }
    if (lane < OUT_) logit[(size_t)b * OUT_ + lane] = acc3;
}

// ---------------------------------------------------------------------------
extern "C" void kernel_launch(void* const* d_in, const int* in_sizes, int n_in,
                              void* d_out, int out_size, void* d_ws, size_t ws_size,
                              hipStream_t stream) {
    const float* input1 = (const float*)d_in[0];
    const float* input2 = (const float*)d_in[1];
    const float* W_ih   = (const float*)d_in[2];
    const float* W_hh   = (const float*)d_in[3];
    const float* b_ih   = (const float*)d_in[4];
    const float* b_hh   = (const float*)d_in[5];
    const float* W1     = (const float*)d_in[6];
    const float* b1     = (const float*)d_in[7];
    const float* W2     = (const float*)d_in[8];
    const float* b2     = (const float*)d_in[9];
    const float* W3     = (const float*)d_in[10];
    const float* b3     = (const float*)d_in[11];

    float* out = (float*)d_out;                 // [5120 logit][153600 emb1]
    float* h2s = (float*)d_ws;                  // 5120*30 floats

    hipLaunchKernelGGL(gru_kernel, dim3(640), dim3(64), 0, stream,
                       input1, input2, W_ih, W_hh, b_ih, b_hh,
                       out + 5120, h2s);
    hipLaunchKernelGGL(mlp_kernel, dim3(512), dim3(64), 0, stream,
                       h2s, W1, b1, W2, b2, W3, b3, out);
}

// Round 6
// 125.440 us; speedup vs baseline: 1.0714x; 1.0714x over previous
//
#include <hip/hip_runtime.h>
#include <hip/hip_bf16.h>
#include <math.h>

#define T_    100
#define D_    50
#define H_    30
#define HALF  5120
#define EMB_  20
#define NEMB_ 10
#define OUT_  10

typedef _Float16 h2    __attribute__((ext_vector_type(2)));
typedef _Float16 f16x8 __attribute__((ext_vector_type(8)));
typedef float    f32x4 __attribute__((ext_vector_type(4)));

union FR  { f16x8 v; h2 p[4]; float4 f4; };
union W64 { h2 hh[2]; float2 f2; };

__device__ __forceinline__ h2 pk(float a, float b) {
    return __builtin_bit_cast(h2, __builtin_amdgcn_cvt_pkrtz(a, b));
}

// named-member x-load buffer (rule: no runtime-indexed arrays -> registers)
struct XR { float2 a0, a1, a2, a3, b0, b1, b2, b3; };

// ---------------------------------------------------------------------------
// GRU: 1 wave per block, 16 sequences per wave. 640 blocks.
// Swapped MFMA: C[g][s] = Wext[g][k] * Bext[s][k]; gate rows padded to
// g = gate*32 + j so lane (s = l&15, q = l>>4) holds the complete (r,z,n)
// triple for j in {16u + 4q + r}. No cross-lane ops, no barriers in the loop.
// Biases fold into MFMA: Hext[s][30] = 1.0 -> b_hh; x col 50 = 1.0 -> b_ih.
// Round 6: depth-4 x prefetch (occupancy is wave-count-bound -> VGPRs free),
// and x-first/h-last MFMA ordering to shorten the serial h chain.
// ---------------------------------------------------------------------------
__global__ __launch_bounds__(64) void gru_kernel(
    const float* __restrict__ input1, const float* __restrict__ input2,
    const float* __restrict__ W_ih,  const float* __restrict__ W_hh,
    const float* __restrict__ b_ih,  const float* __restrict__ b_hh,
    float* __restrict__ emb1_out,    // [5120][30]
    float* __restrict__ h2_out)      // [5120][30]
{
    const int lane = threadIdx.x & 63;
    const int s    = lane & 15;          // seq within wave (and frag row m/n)
    const int q    = lane >> 4;          // k-slice / C row-quad
    const int n    = blockIdx.x * 16 + s;

    __shared__ __align__(16) _Float16 Wst [96 * 64];  // W_ih ext (12 KB)
    __shared__ __align__(16) _Float16 Whst[96 * 32];  // W_hh ext (6 KB)
    __shared__ __align__(16) _Float16 Hl  [16 * 40];  // h rows, stride 40

    // ---- zero W staging (pad rows j=30,31 of each gate block stay 0) ----
    for (int i = lane; i < 1536; i += 64) ((unsigned long long*)Wst)[i]  = 0ull;
    for (int i = lane; i < 768;  i += 64) ((unsigned long long*)Whst)[i] = 0ull;

    // ---- stage W_ih: ext row ge = gate*32 + j, col 50 = b_ih ----
    for (int i = 0; i < 71; ++i) {
        int idx = lane + i * 64;
        if (idx < 4500) {
            int rw = idx / 50, k = idx - rw * 50;
            int ge = rw + 2 * (rw / 30);
            Wst[ge * 64 + k] = (_Float16)W_ih[idx];
        }
    }
    for (int i = 0; i < 2; ++i) {
        int idx = lane + i * 64;
        if (idx < 90) { int ge = idx + 2 * (idx / 30); Wst[ge * 64 + 50] = (_Float16)b_ih[idx]; }
    }
    // ---- stage W_hh: col 30 = b_hh, col 31 = 0 ----
    for (int i = 0; i < 43; ++i) {
        int idx = lane + i * 64;
        if (idx < 2700) {
            int rw = idx / 30, k = idx - rw * 30;
            int ge = rw + 2 * (rw / 30);
            Whst[ge * 32 + k] = (_Float16)W_hh[idx];
        }
    }
    for (int i = 0; i < 2; ++i) {
        int idx = lane + i * 64;
        if (idx < 90) { int ge = idx + 2 * (idx / 30); Whst[ge * 32 + 30] = (_Float16)b_hh[idx]; }
    }
    // ---- h0 = 0; Hl[s][30] = 1.0 (bias one), [31] = 0 ----
    if (lane < 16) {
        for (int j = 0; j < 15; ++j) *(h2*)&Hl[lane * 40 + 2 * j] = pk(0.f, 0.f);
        *(h2*)&Hl[lane * 40 + 30] = pk(1.f, 0.f);
    }
    __syncthreads();

    // ---- A-fragments (weights) into registers ----
    FR wih[6][2], whh[6];
    #pragma unroll
    for (int nt = 0; nt < 6; ++nt) {
        wih[nt][0].f4 = *(const float4*)&Wst [(nt * 16 + s) * 64 + q * 8];
        wih[nt][1].f4 = *(const float4*)&Wst [(nt * 16 + s) * 64 + 32 + q * 8];
        whh[nt].f4    = *(const float4*)&Whst[(nt * 16 + s) * 32 + q * 8];
    }

    // ---- per-lane sequence pointer ----
    const float* xp = (n < HALF) ? input1 + (size_t)n * (T_ * D_)
                                 : input2 + (size_t)(n - HALF) * (T_ * D_);

    auto load_x = [&](int t, XR& X) {
        const float* r = xp + t * D_;
        X.a0 = *(const float2*)(r + q * 8 + 0);
        X.a1 = *(const float2*)(r + q * 8 + 2);
        X.a2 = *(const float2*)(r + q * 8 + 4);
        X.a3 = *(const float2*)(r + q * 8 + 6);
        if (q < 2) {
            X.b0 = *(const float2*)(r + 32 + q * 8 + 0);
            X.b1 = *(const float2*)(r + 32 + q * 8 + 2);
            X.b2 = *(const float2*)(r + 32 + q * 8 + 4);
            X.b3 = *(const float2*)(r + 32 + q * 8 + 6);
        } else if (q == 2) {
            X.b0 = *(const float2*)(r + 48);          // d 48,49
        }
    };
    auto build = [&](const XR& X, FR& x0, FR& x1) {
        x0.p[0] = pk(X.a0.x, X.a0.y); x0.p[1] = pk(X.a1.x, X.a1.y);
        x0.p[2] = pk(X.a2.x, X.a2.y); x0.p[3] = pk(X.a3.x, X.a3.y);
        if (q < 2) {
            x1.p[0] = pk(X.b0.x, X.b0.y); x1.p[1] = pk(X.b1.x, X.b1.y);
            x1.p[2] = pk(X.b2.x, X.b2.y); x1.p[3] = pk(X.b3.x, X.b3.y);
        } else if (q == 2) {
            x1.p[0] = pk(X.b0.x, X.b0.y); x1.p[1] = pk(1.f, 0.f);   // d50 = bias
            x1.p[2] = pk(0.f, 0.f);       x1.p[3] = pk(0.f, 0.f);
        } else {
            x1.p[0] = pk(0.f, 0.f); x1.p[1] = pk(0.f, 0.f);
            x1.p[2] = pk(0.f, 0.f); x1.p[3] = pk(0.f, 0.f);
        }
    };

    float hold[8] = {0.f, 0.f, 0.f, 0.f, 0.f, 0.f, 0.f, 0.f};

    auto step = [&](const FR& x0, const FR& x1) {
        FR bh;
        bh.f4 = *(const float4*)&Hl[s * 40 + q * 8];
        f32x4 arz[4], anh[2], anx[2];
        // ---- x-part MFMAs first (independent of h; overlap the ds_read),
        //      h-dependent MFMA last -> shortest serial link ----
        #pragma unroll
        for (int nt = 0; nt < 4; ++nt) {                 // r,z gates: K = x + h
            f32x4 acc = {0.f, 0.f, 0.f, 0.f};
            acc = __builtin_amdgcn_mfma_f32_16x16x32_f16(wih[nt][0].v, x0.v, acc, 0, 0, 0);
            acc = __builtin_amdgcn_mfma_f32_16x16x32_f16(wih[nt][1].v, x1.v, acc, 0, 0, 0);
            acc = __builtin_amdgcn_mfma_f32_16x16x32_f16(whh[nt].v,    bh.v, acc, 0, 0, 0);
            arz[nt] = acc;
        }
        #pragma unroll
        for (int u = 0; u < 2; ++u) {                    // n gate: h and x SEPARATE
            f32x4 ax = {0.f, 0.f, 0.f, 0.f}, ah = {0.f, 0.f, 0.f, 0.f};
            ax = __builtin_amdgcn_mfma_f32_16x16x32_f16(wih[4 + u][0].v, x0.v, ax, 0, 0, 0);
            ax = __builtin_amdgcn_mfma_f32_16x16x32_f16(wih[4 + u][1].v, x1.v, ax, 0, 0, 0);
            ah = __builtin_amdgcn_mfma_f32_16x16x32_f16(whh[4 + u].v,    bh.v, ah, 0, 0, 0);
            anh[u] = ah; anx[u] = ax;
        }
        #pragma unroll
        for (int u = 0; u < 2; ++u) {
            #pragma unroll
            for (int r = 0; r < 4; ++r) {                // j = 16u + 4q + r
                const float rg = __builtin_amdgcn_rcpf(1.f + __expf(-arz[u][r]));
                const float zg = __builtin_amdgcn_rcpf(1.f + __expf(-arz[2 + u][r]));
                const float aa = fmaf(rg, anh[u][r], anx[u][r]);
                const float th = fmaf(-2.f, __builtin_amdgcn_rcpf(1.f + __expf(2.f * aa)), 1.f);
                hold[u * 4 + r] = fmaf(zg, hold[u * 4 + r] - th, th);
            }
        }
        W64 w0, w1;
        w0.hh[0] = pk(hold[0], hold[1]); w0.hh[1] = pk(hold[2], hold[3]);
        *(float2*)&Hl[s * 40 + 4 * q] = w0.f2;           // j = 4q..4q+3
        if (q < 3) {
            w1.hh[0] = pk(hold[4], hold[5]); w1.hh[1] = pk(hold[6], hold[7]);
            *(float2*)&Hl[s * 40 + 16 + 4 * q] = w1.f2;  // j = 16+4q..+3
        } else {
            *(h2*)&Hl[s * 40 + 28] = pk(hold[4], hold[5]); // j = 28,29 only
        }
    };

    // ---- 100 steps, depth-4 software pipeline on x loads ----
    XR X0, X1, X2, X3;
    load_x(0, X0); load_x(1, X1); load_x(2, X2); load_x(3, X3);
    #pragma unroll 1
    for (int k = 0; k < 25; ++k) {
        const int t = 4 * k;
        const bool more = (k < 24);
        FR x0, x1;
        build(X0, x0, x1); if (more) load_x(t + 4, X0); step(x0, x1);
        build(X1, x0, x1); if (more) load_x(t + 5, X1); step(x0, x1);
        build(X2, x0, x1); if (more) load_x(t + 6, X2); step(x0, x1);
        build(X3, x0, x1); if (more) load_x(t + 7, X3); step(x0, x1);
    }

    // ---- final hidden out (f32 from registers) ----
    float* outp = (n < HALF) ? emb1_out + (size_t)n * H_
                             : h2_out + (size_t)(n - HALF) * H_;
    #pragma unroll
    for (int u = 0; u < 2; ++u)
        #pragma unroll
        for (int r = 0; r < 4; ++r) {
            const int j = 16 * u + 4 * q + r;
            if (j < H_) outp[j] = hold[u * 4 + r];
        }
}

// ---------------------------------------------------------------------------
// MLP head (unchanged): one row per block.
// ---------------------------------------------------------------------------
__global__ __launch_bounds__(64) void mlp_kernel(
    const float* __restrict__ h2i,  // [512][300]
    const float* __restrict__ W1, const float* __restrict__ b1,
    const float* __restrict__ W2, const float* __restrict__ b2,
    const float* __restrict__ W3, const float* __restrict__ b3,
    float* __restrict__ logit)      // [512][10]
{
    const int b    = blockIdx.x;
    const int lane = threadIdx.x;
    __shared__ float e2[300];
    const float* row = h2i + (size_t)b * 300;
    #pragma unroll
    for (int i = lane; i < 75; i += 64)
        *(float4*)&e2[i * 4] = *(const float4*)(row + i * 4);
    __syncthreads();

    const float kInvSqrt2 = 0.70710678118654752f;
    float y1 = 0.f;
    if (lane < EMB_) {
        float acc = b1[lane];
        const float* wp = W1 + lane * 300;
        #pragma unroll
        for (int qq = 0; qq < 75; ++qq) {
            float4 wv = *(const float4*)(wp + qq * 4);
            acc += wv.x * e2[qq*4 + 0] + wv.y * e2[qq*4 + 1]
                 + wv.z * e2[qq*4 + 2] + wv.w * e2[qq*4 + 3];
        }
        y1 = 0.5f * acc * (1.f + erff(acc * kInvSqrt2));
    }
    float acc2 = (lane < NEMB_) ? b2[lane] : 0.f;
    #pragma unroll
    for (int e = 0; e < EMB_; ++e) {
        const float v = __shfl(y1, e);
        if (lane < NEMB_) acc2 += v * W2[lane * EMB_ + e];
    }
    const float y2 = 0.5f * acc2 * (1.f + erff(acc2 * kInvSqrt2));
    float acc3 = (lane < OUT_) ? b3[lane] : 0.f;
    #pragma unroll
    for (int e = 0; e < NEMB_; ++e) {
        const float v = __shfl(y2, e);
        if (lane < OUT_) acc3 += v * W3[lane * NEMB_ + e];
    }
    if (lane < OUT_) logit[(size_t)b * OUT_ + lane] = acc3;
}

// ---------------------------------------------------------------------------
extern "C" void kernel_launch(void* const* d_in, const int* in_sizes, int n_in,
                              void* d_out, int out_size, void* d_ws, size_t ws_size,
                              hipStream_t stream) {
    const float* input1 = (const float*)d_in[0];
    const float* input2 = (const float*)d_in[1];
    const float* W_ih   = (const float*)d_in[2];
    const float* W_hh   = (const float*)d_in[3];
    const float* b_ih   = (const float*)d_in[4];
    const float* b_hh   = (const float*)d_in[5];
    const float* W1     = (const float*)d_in[6];
    const float* b1     = (const float*)d_in[7];
    const float* W2     = (const float*)d_in[8];
    const float* b2     = (const float*)d_in[9];
    const float* W3     = (const float*)d_in[10];
    const float* b3     = (const float*)d_in[11];

    float* out = (float*)d_out;                 // [5120 logit][153600 emb1]
    float* h2s = (float*)d_ws;                  // 5120*30 floats

    hipLaunchKernelGGL(gru_kernel, dim3(640), dim3(64), 0, stream,
                       input1, input2, W_ih, W_hh, b_ih, b_hh,
                       out + 5120, h2s);
    hipLaunchKernelGGL(mlp_kernel, dim3(512), dim3(64), 0, stream,
                       h2s, W1, b1, W2, b2, W3, b3, out);
}

// Round 7
// 123.803 us; speedup vs baseline: 1.0855x; 1.0132x over previous
//
#include <hip/hip_runtime.h>
#include <hip/hip_bf16.h>
#include <math.h>

#define T_    100
#define D_    50
#define H_    30
#define HALF  5120
#define EMB_  20
#define NEMB_ 10
#define OUT_  10

typedef _Float16 h2    __attribute__((ext_vector_type(2)));
typedef _Float16 f16x8 __attribute__((ext_vector_type(8)));
typedef float    f32x4 __attribute__((ext_vector_type(4)));

union FR  { f16x8 v; h2 p[4]; float4 f4; };

__device__ __forceinline__ h2 pk(float a, float b) {
    return __builtin_bit_cast(h2, __builtin_amdgcn_cvt_pkrtz(a, b));
}
__device__ __forceinline__ int pki(float a, float b) {
    return __builtin_bit_cast(int, __builtin_amdgcn_cvt_pkrtz(a, b));
}

struct XR { float2 a0, a1, a2, a3, b0, b1, b2, b3; };

// ---------------------------------------------------------------------------
// GRU: 1 wave per block, 16 sequences per wave. 640 blocks.
// Swapped MFMA: C[g][s] = Wext[g][k] * Hext[s][k]; gate rows g = gate*32 + j
// so lane (s = l&15, q = l>>4) holds the (r,z,n) triple for j = 16u + 4q + r.
// Round 7: h lives in REGISTERS; next step's B-fragment built with 8 __shfl
// + 4 selects (no LDS h round-trip). x prefetch depth = 8.
// Biases fold into MFMA: Hext[30]=1.0 (constant p3) -> b_hh; x[50]=1 -> b_ih.
// ---------------------------------------------------------------------------
__global__ __launch_bounds__(64, 1) void gru_kernel(
    const float* __restrict__ input1, const float* __restrict__ input2,
    const float* __restrict__ W_ih,  const float* __restrict__ W_hh,
    const float* __restrict__ b_ih,  const float* __restrict__ b_hh,
    float* __restrict__ emb1_out,    // [5120][30]
    float* __restrict__ h2_out)      // [5120][30]
{
    const int lane = threadIdx.x & 63;
    const int s    = lane & 15;
    const int q    = lane >> 4;
    const int n    = blockIdx.x * 16 + s;

    __shared__ __align__(16) _Float16 Wst [96 * 64];  // W_ih ext (12 KB)
    __shared__ __align__(16) _Float16 Whst[96 * 32];  // W_hh ext (6 KB)

    for (int i = lane; i < 1536; i += 64) ((unsigned long long*)Wst)[i]  = 0ull;
    for (int i = lane; i < 768;  i += 64) ((unsigned long long*)Whst)[i] = 0ull;

    for (int i = 0; i < 71; ++i) {
        int idx = lane + i * 64;
        if (idx < 4500) {
            int rw = idx / 50, k = idx - rw * 50;
            int ge = rw + 2 * (rw / 30);
            Wst[ge * 64 + k] = (_Float16)W_ih[idx];
        }
    }
    for (int i = 0; i < 2; ++i) {
        int idx = lane + i * 64;
        if (idx < 90) { int ge = idx + 2 * (idx / 30); Wst[ge * 64 + 50] = (_Float16)b_ih[idx]; }
    }
    for (int i = 0; i < 43; ++i) {
        int idx = lane + i * 64;
        if (idx < 2700) {
            int rw = idx / 30, k = idx - rw * 30;
            int ge = rw + 2 * (rw / 30);
            Whst[ge * 32 + k] = (_Float16)W_hh[idx];
        }
    }
    for (int i = 0; i < 2; ++i) {
        int idx = lane + i * 64;
        if (idx < 90) { int ge = idx + 2 * (idx / 30); Whst[ge * 32 + 30] = (_Float16)b_hh[idx]; }
    }
    __syncthreads();

    FR wih[6][2], whh[6];
    #pragma unroll
    for (int nt = 0; nt < 6; ++nt) {
        wih[nt][0].f4 = *(const float4*)&Wst [(nt * 16 + s) * 64 + q * 8];
        wih[nt][1].f4 = *(const float4*)&Wst [(nt * 16 + s) * 64 + 32 + q * 8];
        whh[nt].f4    = *(const float4*)&Whst[(nt * 16 + s) * 32 + q * 8];
    }

    const float* xp = (n < HALF) ? input1 + (size_t)n * (T_ * D_)
                                 : input2 + (size_t)(n - HALF) * (T_ * D_);

    auto load_x = [&](int t, XR& X) {
        const float* r = xp + t * D_;
        X.a0 = *(const float2*)(r + q * 8 + 0);
        X.a1 = *(const float2*)(r + q * 8 + 2);
        X.a2 = *(const float2*)(r + q * 8 + 4);
        X.a3 = *(const float2*)(r + q * 8 + 6);
        if (q < 2) {
            X.b0 = *(const float2*)(r + 32 + q * 8 + 0);
            X.b1 = *(const float2*)(r + 32 + q * 8 + 2);
            X.b2 = *(const float2*)(r + 32 + q * 8 + 4);
            X.b3 = *(const float2*)(r + 32 + q * 8 + 6);
        } else if (q == 2) {
            X.b0 = *(const float2*)(r + 48);
        }
    };
    auto build = [&](const XR& X, FR& x0, FR& x1) {
        x0.p[0] = pk(X.a0.x, X.a0.y); x0.p[1] = pk(X.a1.x, X.a1.y);
        x0.p[2] = pk(X.a2.x, X.a2.y); x0.p[3] = pk(X.a3.x, X.a3.y);
        if (q < 2) {
            x1.p[0] = pk(X.b0.x, X.b0.y); x1.p[1] = pk(X.b1.x, X.b1.y);
            x1.p[2] = pk(X.b2.x, X.b2.y); x1.p[3] = pk(X.b3.x, X.b3.y);
        } else if (q == 2) {
            x1.p[0] = pk(X.b0.x, X.b0.y); x1.p[1] = pk(1.f, 0.f);
            x1.p[2] = pk(0.f, 0.f);       x1.p[3] = pk(0.f, 0.f);
        } else {
            x1.p[0] = pk(0.f, 0.f); x1.p[1] = pk(0.f, 0.f);
            x1.p[2] = pk(0.f, 0.f); x1.p[3] = pk(0.f, 0.f);
        }
    };

    float hold[8] = {0.f, 0.f, 0.f, 0.f, 0.f, 0.f, 0.f, 0.f};
    int w0 = 0, w1 = 0, w2 = 0, w3 = 0;
    const int la = ((2 * q) & 3) * 16 + s;
    const int lb = ((2 * q + 1) & 3) * 16 + s;
    const int ONE = pki(1.f, 0.f);

    auto step = [&](const FR& x0, const FR& x1) {
        const int A0 = __shfl(w0, la), A1 = __shfl(w1, la);
        const int A2 = __shfl(w2, la), A3 = __shfl(w3, la);
        const int B0 = __shfl(w0, lb), B1 = __shfl(w1, lb);
        const int B2 = __shfl(w2, lb), B3 = __shfl(w3, lb);
        FR bh;
        bh.p[0] = __builtin_bit_cast(h2, q < 2 ? A0 : A2);
        bh.p[1] = __builtin_bit_cast(h2, q < 2 ? A1 : A3);
        bh.p[2] = __builtin_bit_cast(h2, q < 2 ? B0 : B2);
        bh.p[3] = __builtin_bit_cast(h2, q == 3 ? ONE : (q < 2 ? B1 : B3));

        f32x4 arz[4], anh[2], anx[2];
        #pragma unroll
        for (int nt = 0; nt < 4; ++nt) {
            f32x4 acc = {0.f, 0.f, 0.f, 0.f};
            acc = __builtin_amdgcn_mfma_f32_16x16x32_f16(wih[nt][0].v, x0.v, acc, 0, 0, 0);
            acc = __builtin_amdgcn_mfma_f32_16x16x32_f16(wih[nt][1].v, x1.v, acc, 0, 0, 0);
            acc = __builtin_amdgcn_mfma_f32_16x16x32_f16(whh[nt].v,    bh.v, acc, 0, 0, 0);
            arz[nt] = acc;
        }
        #pragma unroll
        for (int u = 0; u < 2; ++u) {
            f32x4 ax = {0.f, 0.f, 0.f, 0.f}, ah = {0.f, 0.f, 0.f, 0.f};
            ax = __builtin_amdgcn_mfma_f32_16x16x32_f16(wih[4 + u][0].v, x0.v, ax, 0, 0, 0);
            ax = __builtin_amdgcn_mfma_f32_16x16x32_f16(wih[4 + u][1].v, x1.v, ax, 0, 0, 0);
            ah = __builtin_amdgcn_mfma_f32_16x16x32_f16(whh[4 + u].v,    bh.v, ah, 0, 0, 0);
            anh[u] = ah; anx[u] = ax;
        }
        #pragma unroll
        for (int u = 0; u < 2; ++u) {
            #pragma unroll
            for (int r = 0; r < 4; ++r) {
                const float rg = __builtin_amdgcn_rcpf(1.f + __expf(-arz[u][r]));
                const float zg = __builtin_amdgcn_rcpf(1.f + __expf(-arz[2 + u][r]));
                const float aa = fmaf(rg, anh[u][r], anx[u][r]);
                const float th = fmaf(-2.f, __builtin_amdgcn_rcpf(1.f + __expf(2.f * aa)), 1.f);
                hold[u * 4 + r] = fmaf(zg, hold[u * 4 + r] - th, th);
            }
        }
        w0 = pki(hold[0], hold[1]); w1 = pki(hold[2], hold[3]);
        w2 = pki(hold[4], hold[5]); w3 = pki(hold[6], hold[7]);
    };

    XR X0, X1, X2, X3, X4, X5, X6, X7;
    load_x(0, X0); load_x(1, X1); load_x(2, X2); load_x(3, X3);
    load_x(4, X4); load_x(5, X5); load_x(6, X6); load_x(7, X7);
    #pragma unroll 1
    for (int k = 0; k < 12; ++k) {
        const int t = 8 * k;
        FR x0, x1;
        build(X0, x0, x1); if (t +  8 < 100) load_x(t +  8, X0); step(x0, x1);
        build(X1, x0, x1); if (t +  9 < 100) load_x(t +  9, X1); step(x0, x1);
        build(X2, x0, x1); if (t + 10 < 100) load_x(t + 10, X2); step(x0, x1);
        build(X3, x0, x1); if (t + 11 < 100) load_x(t + 11, X3); step(x0, x1);
        build(X4, x0, x1); if (t + 12 < 100) load_x(t + 12, X4); step(x0, x1);
        build(X5, x0, x1); if (t + 13 < 100) load_x(t + 13, X5); step(x0, x1);
        build(X6, x0, x1); if (t + 14 < 100) load_x(t + 14, X6); step(x0, x1);
        build(X7, x0, x1); if (t + 15 < 100) load_x(t + 15, X7); step(x0, x1);
    }
    {   // tail: t = 96..99, loaded during k=11 into X0..X3
        FR x0, x1;
        build(X0, x0, x1); step(x0, x1);
        build(X1, x0, x1); step(x0, x1);
        build(X2, x0, x1); step(x0, x1);
        build(X3, x0, x1); step(x0, x1);
    }

    float* outp = (n < HALF) ? emb1_out + (size_t)n * H_
                             : h2_out + (size_t)(n - HALF) * H_;
    #pragma unroll
    for (int u = 0; u < 2; ++u)
        #pragma unroll
        for (int r = 0; r < 4; ++r) {
            const int j = 16 * u + 4 * q + r;
            if (j < H_) outp[j] = hold[u * 4 + r];
        }
}

// ---------------------------------------------------------------------------
__global__ __launch_bounds__(64) void mlp_kernel(
    const float* __restrict__ h2i,
    const float* __restrict__ W1, const float* __restrict__ b1,
    const float* __restrict__ W2, const float* __restrict__ b2,
    const float* __restrict__ W3, const float* __restrict__ b3,
    float* __restrict__ logit)
{
    const int b    = blockIdx.x;
    const int lane = threadIdx.x;
    __shared__ float e2[300];
    const float* row = h2i + (size_t)b * 300;
    #pragma unroll
    for (int i = lane; i < 75; i += 64)
        *(float4*)&e2[i * 4] = *(const float4*)(row + i * 4);
    __syncthreads();

    const float kInvSqrt2 = 0.70710678118654752f;
    float y1 = 0.f;
    if (lane < EMB_) {
        float acc = b1[lane];
        const float* wp = W1 + lane * 300;
        #pragma unroll
        for (int qq = 0; qq < 75; ++qq) {
            float4 wv = *(const float4*)(wp + qq * 4);
            acc += wv.x * e2[qq*4 + 0] + wv.y * e2[qq*4 + 1]
                 + wv.z * e2[qq*4 + 2] + wv.w * e2[qq*4 + 3];
        }
        y1 = 0.5f * acc * (1.f + erff(acc * kInvSqrt2));
    }
    float acc2 = (lane < NEMB_) ? b2[lane] : 0.f;
    #pragma unroll
    for (int e = 0; e < EMB_; ++e) {
        const float v = __shfl(y1, e);
        if (lane < NEMB_) acc2 += v * W2[lane * EMB_ + e];
    }
    const float y2 = 0.5f * acc2 * (1.f + erff(acc2 * kInvSqrt2));
    float acc3 = (lane < OUT_) ? b3[lane] : 0.f;
    #pragma unroll
    for (int e = 0; e < NEMB_; ++e) {
        const float v = __shfl(y2, e);
        if (lane < OUT_) acc3 += v * W3[lane * NEMB_ + e];
    }
    if (lane < OUT_) logit[(size_t)b * OUT_ + lane] = acc3;
}

// ---------------------------------------------------------------------------
extern "C" void kernel_launch(void* const* d_in, const int* in_sizes, int n_in,
                              void* d_out, int out_size, void* d_ws, size_t ws_size,
                              hipStream_t stream) {
    const float* input1 = (const float*)d_in[0];
    const float* input2 = (const float*)d_in[1];
    const float* W_ih   = (const float*)d_in[2];
    const float* W_hh   = (const float*)d_in[3];
    const float* b_ih   = (const float*)d_in[4];
    const float* b_hh   = (const float*)d_in[5];
    const float* W1     = (const float*)d_in[6];
    const float* b1     = (const float*)d_in[7];
    const float* W2     = (const float*)d_in[8];
    const float* b2     = (const float*)d_in[9];
    const float* W3     = (const float*)d_in[10];
    const float* b3     = (const float*)d_in[11];

    float* out = (float*)d_out;
    float* h2s = (float*)d_ws;

    hipLaunchKernelGGL(gru_kernel, dim3(640), dim3(64), 0, stream,
                       input1, input2, W_ih, W_hh, b_ih, b_hh,
                       out + 5120, h2s);
    hipLaunchKernelGGL(mlp_kernel, dim3(512), dim3(64), 0, stream,
                       h2s, W1, b1, W2, b2, W3, b3, out);
}

// Round 8
// 110.582 us; speedup vs baseline: 1.2153x; 1.1196x over previous
//
#include <hip/hip_runtime.h>
#include <hip/hip_bf16.h>
#include <math.h>

#define T_    100
#define D_    50
#define H_    30
#define HALF  5120
#define EMB_  20
#define NEMB_ 10
#define OUT_  10

typedef _Float16 h2    __attribute__((ext_vector_type(2)));
typedef _Float16 f16x8 __attribute__((ext_vector_type(8)));
typedef float    f32x4 __attribute__((ext_vector_type(4)));

union FR  { f16x8 v; h2 p[4]; float4 f4; };

__device__ __forceinline__ h2 pk(float a, float b) {
    return __builtin_bit_cast(h2, __builtin_amdgcn_cvt_pkrtz(a, b));
}
__device__ __forceinline__ int pki(float a, float b) {
    return __builtin_bit_cast(int, __builtin_amdgcn_cvt_pkrtz(a, b));
}

#if __has_builtin(__builtin_amdgcn_exp2f)
#define EXP2(x) __builtin_amdgcn_exp2f(x)
#else
#define EXP2(x) exp2f(x)
#endif

struct XR { float2 a0, a1, a2, a3, b0, b1, b2, b3; };

// ---------------------------------------------------------------------------
// GRU: 1 wave per block, 16 sequences per wave. 640 blocks.
// Swapped MFMA: C[g][s] = Wext[g][k] * Hext[s][k]; gate rows g = gate*32 + j
// so lane (s = l&15, q = l>>4) holds the (r,z,n) triple for j = 16u + 4q + r.
// h lives in registers; B-frag rebuilt per step with 8 bpermute + selects.
// Round 8: ALL prefetch loads unconditional & branch-free (clamped step
// index, pointer-select tails) so the compiler can emit counted vmcnt(N)
// instead of a conservative drain; log2e scales folded into staged weights
// so gates use raw v_exp_f32 (exp2) with no pre-multiply.
// Biases fold into MFMA: Hext[30]=1.0 (constant p3) -> b_hh; x[50]=1 -> b_ih.
// ---------------------------------------------------------------------------
__global__ __launch_bounds__(64, 1) void gru_kernel(
    const float* __restrict__ input1, const float* __restrict__ input2,
    const float* __restrict__ W_ih,  const float* __restrict__ W_hh,
    const float* __restrict__ b_ih,  const float* __restrict__ b_hh,
    float* __restrict__ emb1_out,    // [5120][30]
    float* __restrict__ h2_out)      // [5120][30]
{
    const int lane = threadIdx.x & 63;
    const int s    = lane & 15;
    const int q    = lane >> 4;
    const int n    = blockIdx.x * 16 + s;

    __shared__ __align__(16) _Float16 Wst [96 * 64];  // W_ih ext (12 KB)
    __shared__ __align__(16) _Float16 Whst[96 * 32];  // W_hh ext (6 KB)

    // gate scales: r,z rows * -log2(e)  -> sigmoid(a) = rcp(1+exp2(aS))
    //              n   rows * +2log2(e) -> tanh(a)    = 1-2*rcp(1+exp2(aS))
    const float SC_RZ = -1.4426950408889634f;
    const float SC_N  =  2.8853900817779268f;

    for (int i = lane; i < 1536; i += 64) ((unsigned long long*)Wst)[i]  = 0ull;
    for (int i = lane; i < 768;  i += 64) ((unsigned long long*)Whst)[i] = 0ull;

    for (int i = 0; i < 71; ++i) {
        int idx = lane + i * 64;
        if (idx < 4500) {
            int rw = idx / 50, k = idx - rw * 50;
            int g  = rw / 30;
            int ge = rw + 2 * g;
            float sc = (g < 2) ? SC_RZ : SC_N;
            Wst[ge * 64 + k] = (_Float16)(W_ih[idx] * sc);
        }
    }
    for (int i = 0; i < 2; ++i) {
        int idx = lane + i * 64;
        if (idx < 90) {
            int g = idx / 30; int ge = idx + 2 * g;
            float sc = (g < 2) ? SC_RZ : SC_N;
            Wst[ge * 64 + 50] = (_Float16)(b_ih[idx] * sc);
        }
    }
    for (int i = 0; i < 43; ++i) {
        int idx = lane + i * 64;
        if (idx < 2700) {
            int rw = idx / 30, k = idx - rw * 30;
            int g  = rw / 30;
            int ge = rw + 2 * g;
            float sc = (g < 2) ? SC_RZ : SC_N;
            Whst[ge * 32 + k] = (_Float16)(W_hh[idx] * sc);
        }
    }
    for (int i = 0; i < 2; ++i) {
        int idx = lane + i * 64;
        if (idx < 90) {
            int g = idx / 30; int ge = idx + 2 * g;
            float sc = (g < 2) ? SC_RZ : SC_N;
            Whst[ge * 32 + 30] = (_Float16)(b_hh[idx] * sc);
        }
    }
    __syncthreads();

    FR wih[6][2], whh[6];
    #pragma unroll
    for (int nt = 0; nt < 6; ++nt) {
        wih[nt][0].f4 = *(const float4*)&Wst [(nt * 16 + s) * 64 + q * 8];
        wih[nt][1].f4 = *(const float4*)&Wst [(nt * 16 + s) * 64 + 32 + q * 8];
        whh[nt].f4    = *(const float4*)&Whst[(nt * 16 + s) * 32 + q * 8];
    }

    const float* xp = (n < HALF) ? input1 + (size_t)n * (T_ * D_)
                                 : input2 + (size_t)(n - HALF) * (T_ * D_);

    // branch-free: ALWAYS 8 float2 loads; q>=2 tail addresses clamped to
    // valid row memory (values masked in build). Keeps vmcnt statically
    // countable -> compiler emits counted s_waitcnt vmcnt(N), no drain.
    auto load_x = [&](int t, XR& X) {
        const float* r  = xp + t * D_;
        const float* pa = r + q * 8;
        const float* pb = (q < 2) ? (r + 32 + q * 8) : r;   // cndmask select
        const float* p0 = (q == 2) ? (r + 48) : pb;
        X.a0 = *(const float2*)(pa + 0);
        X.a1 = *(const float2*)(pa + 2);
        X.a2 = *(const float2*)(pa + 4);
        X.a3 = *(const float2*)(pa + 6);
        X.b0 = *(const float2*)(p0);
        X.b1 = *(const float2*)(pb + 2);
        X.b2 = *(const float2*)(pb + 4);
        X.b3 = *(const float2*)(pb + 6);
    };
    auto build = [&](const XR& X, FR& x0, FR& x1) {
        x0.p[0] = pk(X.a0.x, X.a0.y); x0.p[1] = pk(X.a1.x, X.a1.y);
        x0.p[2] = pk(X.a2.x, X.a2.y); x0.p[3] = pk(X.a3.x, X.a3.y);
        if (q < 2) {
            x1.p[0] = pk(X.b0.x, X.b0.y); x1.p[1] = pk(X.b1.x, X.b1.y);
            x1.p[2] = pk(X.b2.x, X.b2.y); x1.p[3] = pk(X.b3.x, X.b3.y);
        } else if (q == 2) {
            x1.p[0] = pk(X.b0.x, X.b0.y); x1.p[1] = pk(1.f, 0.f);   // d50 = bias
            x1.p[2] = pk(0.f, 0.f);       x1.p[3] = pk(0.f, 0.f);
        } else {
            x1.p[0] = pk(0.f, 0.f); x1.p[1] = pk(0.f, 0.f);
            x1.p[2] = pk(0.f, 0.f); x1.p[3] = pk(0.f, 0.f);
        }
    };

    float hold[8] = {0.f, 0.f, 0.f, 0.f, 0.f, 0.f, 0.f, 0.f};
    int w0 = 0, w1 = 0, w2 = 0, w3 = 0;
    const int la = ((2 * q) & 3) * 16 + s;
    const int lb = ((2 * q + 1) & 3) * 16 + s;
    const int ONE = pki(1.f, 0.f);

    auto step = [&](const FR& x0, const FR& x1) {
        const int A0 = __shfl(w0, la), A1 = __shfl(w1, la);
        const int A2 = __shfl(w2, la), A3 = __shfl(w3, la);
        const int B0 = __shfl(w0, lb), B1 = __shfl(w1, lb);
        const int B2 = __shfl(w2, lb), B3 = __shfl(w3, lb);
        FR bh;
        bh.p[0] = __builtin_bit_cast(h2, q < 2 ? A0 : A2);
        bh.p[1] = __builtin_bit_cast(h2, q < 2 ? A1 : A3);
        bh.p[2] = __builtin_bit_cast(h2, q < 2 ? B0 : B2);
        bh.p[3] = __builtin_bit_cast(h2, q == 3 ? ONE : (q < 2 ? B1 : B3));

        f32x4 arz[4], anh[2], anx[2];
        #pragma unroll
        for (int nt = 0; nt < 4; ++nt) {
            f32x4 acc = {0.f, 0.f, 0.f, 0.f};
            acc = __builtin_amdgcn_mfma_f32_16x16x32_f16(wih[nt][0].v, x0.v, acc, 0, 0, 0);
            acc = __builtin_amdgcn_mfma_f32_16x16x32_f16(wih[nt][1].v, x1.v, acc, 0, 0, 0);
            acc = __builtin_amdgcn_mfma_f32_16x16x32_f16(whh[nt].v,    bh.v, acc, 0, 0, 0);
            arz[nt] = acc;
        }
        #pragma unroll
        for (int u = 0; u < 2; ++u) {
            f32x4 ax = {0.f, 0.f, 0.f, 0.f}, ah = {0.f, 0.f, 0.f, 0.f};
            ax = __builtin_amdgcn_mfma_f32_16x16x32_f16(wih[4 + u][0].v, x0.v, ax, 0, 0, 0);
            ax = __builtin_amdgcn_mfma_f32_16x16x32_f16(wih[4 + u][1].v, x1.v, ax, 0, 0, 0);
            ah = __builtin_amdgcn_mfma_f32_16x16x32_f16(whh[4 + u].v,    bh.v, ah, 0, 0, 0);
            anh[u] = ah; anx[u] = ax;
        }
        #pragma unroll
        for (int u = 0; u < 2; ++u) {
            #pragma unroll
            for (int r = 0; r < 4; ++r) {
                const float rg = __builtin_amdgcn_rcpf(1.f + EXP2(arz[u][r]));
                const float zg = __builtin_amdgcn_rcpf(1.f + EXP2(arz[2 + u][r]));
                const float aa = fmaf(rg, anh[u][r], anx[u][r]);
                const float th = fmaf(-2.f, __builtin_amdgcn_rcpf(1.f + EXP2(aa)), 1.f);
                hold[u * 4 + r] = fmaf(zg, hold[u * 4 + r] - th, th);
            }
        }
        w0 = pki(hold[0], hold[1]); w1 = pki(hold[2], hold[3]);
        w2 = pki(hold[4], hold[5]); w3 = pki(hold[6], hold[7]);
    };

    XR X0, X1, X2, X3, X4, X5, X6, X7;
    load_x(0, X0); load_x(1, X1); load_x(2, X2); load_x(3, X3);
    load_x(4, X4); load_x(5, X5); load_x(6, X6); load_x(7, X7);
    #pragma unroll 1
    for (int k = 0; k < 12; ++k) {
        const int t = 8 * k;
        FR x0, x1;
        // reloads unconditional, step index clamped (k=11 -> X0..X3 get
        // 96..99 for the tail; X4..X7 get harmless re-reads of t=99)
        build(X0, x0, x1); load_x(t +  8 < 100 ? t +  8 : 99, X0); step(x0, x1);
        build(X1, x0, x1); load_x(t +  9 < 100 ? t +  9 : 99, X1); step(x0, x1);
        build(X2, x0, x1); load_x(t + 10 < 100 ? t + 10 : 99, X2); step(x0, x1);
        build(X3, x0, x1); load_x(t + 11 < 100 ? t + 11 : 99, X3); step(x0, x1);
        build(X4, x0, x1); load_x(t + 12 < 100 ? t + 12 : 99, X4); step(x0, x1);
        build(X5, x0, x1); load_x(t + 13 < 100 ? t + 13 : 99, X5); step(x0, x1);
        build(X6, x0, x1); load_x(t + 14 < 100 ? t + 14 : 99, X6); step(x0, x1);
        build(X7, x0, x1); load_x(t + 15 < 100 ? t + 15 : 99, X7); step(x0, x1);
    }
    {   // tail: t = 96..99, loaded during k=11 into X0..X3
        FR x0, x1;
        build(X0, x0, x1); step(x0, x1);
        build(X1, x0, x1); step(x0, x1);
        build(X2, x0, x1); step(x0, x1);
        build(X3, x0, x1); step(x0, x1);
    }

    float* outp = (n < HALF) ? emb1_out + (size_t)n * H_
                             : h2_out + (size_t)(n - HALF) * H_;
    #pragma unroll
    for (int u = 0; u < 2; ++u)
        #pragma unroll
        for (int r = 0; r < 4; ++r) {
            const int j = 16 * u + 4 * q + r;
            if (j < H_) outp[j] = hold[u * 4 + r];
        }
}

// ---------------------------------------------------------------------------
__global__ __launch_bounds__(64) void mlp_kernel(
    const float* __restrict__ h2i,
    const float* __restrict__ W1, const float* __restrict__ b1,
    const float* __restrict__ W2, const float* __restrict__ b2,
    const float* __restrict__ W3, const float* __restrict__ b3,
    float* __restrict__ logit)
{
    const int b    = blockIdx.x;
    const int lane = threadIdx.x;
    __shared__ float e2[300];
    const float* row = h2i + (size_t)b * 300;
    #pragma unroll
    for (int i = lane; i < 75; i += 64)
        *(float4*)&e2[i * 4] = *(const float4*)(row + i * 4);
    __syncthreads();

    const float kInvSqrt2 = 0.70710678118654752f;
    float y1 = 0.f;
    if (lane < EMB_) {
        float acc = b1[lane];
        const float* wp = W1 + lane * 300;
        #pragma unroll
        for (int qq = 0; qq < 75; ++qq) {
            float4 wv = *(const float4*)(wp + qq * 4);
            acc += wv.x * e2[qq*4 + 0] + wv.y * e2[qq*4 + 1]
                 + wv.z * e2[qq*4 + 2] + wv.w * e2[qq*4 + 3];
        }
        y1 = 0.5f * acc * (1.f + erff(acc * kInvSqrt2));
    }
    float acc2 = (lane < NEMB_) ? b2[lane] : 0.f;
    #pragma unroll
    for (int e = 0; e < EMB_; ++e) {
        const float v = __shfl(y1, e);
        if (lane < NEMB_) acc2 += v * W2[lane * EMB_ + e];
    }
    const float y2 = 0.5f * acc2 * (1.f + erff(acc2 * kInvSqrt2));
    float acc3 = (lane < OUT_) ? b3[lane] : 0.f;
    #pragma unroll
    for (int e = 0; e < NEMB_; ++e) {
        const float v = __shfl(y2, e);
        if (lane < OUT_) acc3 += v * W3[lane * NEMB_ + e];
    }
    if (lane < OUT_) logit[(size_t)b * OUT_ + lane] = acc3;
}

// ---------------------------------------------------------------------------
extern "C" void kernel_launch(void* const* d_in, const int* in_sizes, int n_in,
                              void* d_out, int out_size, void* d_ws, size_t ws_size,
                              hipStream_t stream) {
    const float* input1 = (const float*)d_in[0];
    const float* input2 = (const float*)d_in[1];
    const float* W_ih   = (const float*)d_in[2];
    const float* W_hh   = (const float*)d_in[3];
    const float* b_ih   = (const float*)d_in[4];
    const float* b_hh   = (const float*)d_in[5];
    const float* W1     = (const float*)d_in[6];
    const float* b1     = (const float*)d_in[7];
    const float* W2     = (const float*)d_in[8];
    const float* b2     = (const float*)d_in[9];
    const float* W3     = (const float*)d_in[10];
    const float* b3     = (const float*)d_in[11];

    float* out = (float*)d_out;
    float* h2s = (float*)d_ws;

    hipLaunchKernelGGL(gru_kernel, dim3(640), dim3(64), 0, stream,
                       input1, input2, W_ih, W_hh, b_ih, b_hh,
                       out + 5120, h2s);
    hipLaunchKernelGGL(mlp_kernel, dim3(512), dim3(64), 0, stream,
                       h2s, W1, b1, W2, b2, W3, b3, out);
}